// Round 1
// baseline (107.692 us; speedup 1.0000x reference)
//
#include <hip/hip_runtime.h>
#include <math.h>

// features: (1,50,50,1024) fp32 NHWC; boxes: (1,300,4) [y1,x1,y2,x2] in [0,1]
// CROP=14, POOL_K=2 -> out (1,300,7,7,1024) fp32
//
// R6: WORKSPACE-FREE. rocprof showed the dominant timed dispatches were
// 256 MiB fillBufferAligned re-poisons of the workspace (46 us each, every
// iteration) -- more than the entire pool kernel (<46 us). The bf16-in-ws
// trick saved ~10 us of cache reads but bought a 46 us poison. Net loss.
// This version is a single fp32 kernel: no ws, no cvt pass. It keeps the
// proven structure: 8512 single-wave blocks (TLP), XCD box affinity,
// rolling 4x2 column register cache, 1-column software prefetch, NT stores.
#define FH 50
#define FW 50
#define FC 1024
#define FC4 256        // float4s per pixel
#define NBOX 300
#define PO 7
#define CHQ 4          // channel quarters (64 thr x 4 ch = 256 ch)

typedef float nat4 __attribute__((ext_vector_type(4)));

__device__ __forceinline__ nat4 lerp4(nat4 a, nat4 b, float w) {
    return a + (b - a) * w;
}
__device__ __forceinline__ nat4 max4(nat4 a, nat4 b) {
    nat4 r;
    r.x = fmaxf(a.x, b.x);
    r.y = fmaxf(a.y, b.y);
    r.z = fmaxf(a.z, b.z);
    r.w = fmaxf(a.w, b.w);
    return r;
}

// One SINGLE-WAVE block per (box, pooled row, channel-quarter).
// Rolling 4x2 fp32 column cache with a 1-column software prefetch: loads
// for column ix+1 are issued before computing sample ix, so the vmcnt wait
// for each round overlaps one full compute phase. 8512 single-wave blocks
// keep TLP high. Feature map (10 MB fp32) is L2/L3-resident, so fp32 reads
// cost cache bandwidth, which this kernel is far from saturating.
__global__ __launch_bounds__(64) void roi_pool_f32_kernel(
    const float* __restrict__ feat,    // (50,50,1024) fp32
    const float* __restrict__ boxes,   // (300,4)
    float* __restrict__ out)           // (300,7,7,1024)
{
    const int j = blockIdx.x & 7;              // XCD slot
    const int k = blockIdx.x >> 3;
    const int n = j + 8 * (k / (PO * CHQ));    // box->XCD affinity
    if (n >= NBOX) return;
    const int r  = k % (PO * CHQ);
    const int py = r >> 2;                     // pooled row 0..6
    const int cq = r & 3;                      // channel quarter 0..3
    const int c  = cq * 64 + threadIdx.x;      // float4 index in pixel, 0..255

    const float by1 = boxes[n * 4 + 0];
    const float bx1 = boxes[n * 4 + 1];
    const float by2 = boxes[n * 4 + 2];
    const float bx2 = boxes[n * 4 + 3];

    const float stepy = (by2 - by1) * (49.0f / 13.0f);
    const float stepx = (bx2 - bx1) * (49.0f / 13.0f);
    const float basey = by1 * 49.0f;
    const float basex = bx1 * 49.0f;

    // Two crop rows (2*py, 2*py+1) feed one pooled row.
    const float ysA = basey + (float)(2 * py) * stepy;
    const float ysB = ysA + stepy;
    const float fA = floorf(ysA); const float wyA = ysA - fA;
    const float fB = floorf(ysB); const float wyB = ysB - fB;
    const int y0A = min(max((int)fA, 0), FH - 1); const int y1A = min(y0A + 1, FH - 1);
    const int y0B = min(max((int)fB, 0), FH - 1); const int y1B = min(y0B + 1, FH - 1);

    const nat4* __restrict__ f4 = reinterpret_cast<const nat4*>(feat);
    const int r0 = y0A * FW, r1 = y1A * FW, r2 = y0B * FW, r3 = y1B * FW;

    // cur: fp32 pixels at cols (cc, min(cc+1,49)) for the 4 rows.
    nat4 c00, c01, c10, c11, c20, c21, c30, c31;   // [row][col]
    nat4 n00, n01, n10, n11, n20, n21, n30, n31;   // incoming

    // Prologue: load sample-0 columns (the one unavoidable stall).
    int cc;
    {
        const float xf = floorf(basex);
        cc = min(max((int)xf, 0), FW - 1);
        const int x1 = min(cc + 1, FW - 1);
        c00 = f4[(r0 + cc) * FC4 + c];  c01 = f4[(r0 + x1) * FC4 + c];
        c10 = f4[(r1 + cc) * FC4 + c];  c11 = f4[(r1 + x1) * FC4 + c];
        c20 = f4[(r2 + cc) * FC4 + c];  c21 = f4[(r2 + x1) * FC4 + c];
        c30 = f4[(r3 + cc) * FC4 + c];  c31 = f4[(r3 + x1) * FC4 + c];
    }

    nat4 m = (nat4)(-INFINITY);
    nat4* __restrict__ obase =
        reinterpret_cast<nat4*>(out) + (size_t)(n * (PO * PO) + py * PO) * FC4 + c;

    for (int ix = 0; ix < 2 * PO; ++ix) {
        // ---- Prefetch: issue loads for column ix+1 (no load dependence) ----
        int d = 0;
        if (ix < 2 * PO - 1) {
            const float xsn = basex + (float)(ix + 1) * stepx;
            const int nx0 = min(max((int)floorf(xsn), 0), FW - 1);
            const int nx1 = min(nx0 + 1, FW - 1);
            d = nx0 - cc;
            if (d == 1) {
                n01 = f4[(r0 + nx1) * FC4 + c];
                n11 = f4[(r1 + nx1) * FC4 + c];
                n21 = f4[(r2 + nx1) * FC4 + c];
                n31 = f4[(r3 + nx1) * FC4 + c];
            } else if (d >= 2) {
                n00 = f4[(r0 + nx0) * FC4 + c];  n01 = f4[(r0 + nx1) * FC4 + c];
                n10 = f4[(r1 + nx0) * FC4 + c];  n11 = f4[(r1 + nx1) * FC4 + c];
                n20 = f4[(r2 + nx0) * FC4 + c];  n21 = f4[(r2 + nx1) * FC4 + c];
                n30 = f4[(r3 + nx0) * FC4 + c];  n31 = f4[(r3 + nx1) * FC4 + c];
            }
            cc = nx0;
        }

        // ---- Compute sample ix from current registers ----
        {
            const float xs = basex + (float)ix * stepx;
            const float wx = xs - floorf(xs);   // unclipped floor for the weight
            const nat4 vA = lerp4(lerp4(c00, c01, wx), lerp4(c10, c11, wx), wyA);
            const nat4 vB = lerp4(lerp4(c20, c21, wx), lerp4(c30, c31, wx), wyB);
            m = max4(m, max4(vA, vB));
        }

        if (ix & 1) {
            // write-once output: NT store keeps it out of L1/L2
            __builtin_nontemporal_store(m, obase + (ix >> 1) * FC4);
            m = (nat4)(-INFINITY);
        }

        // ---- Rotate incoming -> current (wave-uniform branches) ----
        if (ix < 2 * PO - 1) {
            if (d == 1) {
                c00 = c01; c10 = c11; c20 = c21; c30 = c31;
                c01 = n01; c11 = n11; c21 = n21; c31 = n31;
            } else if (d >= 2) {
                c00 = n00; c01 = n01; c10 = n10; c11 = n11;
                c20 = n20; c21 = n21; c30 = n30; c31 = n31;
            }
        }
    }
}

extern "C" void kernel_launch(void* const* d_in, const int* in_sizes, int n_in,
                              void* d_out, int out_size, void* d_ws, size_t ws_size,
                              hipStream_t stream) {
    (void)in_sizes; (void)n_in; (void)out_size; (void)d_ws; (void)ws_size;
    const float* feat  = (const float*)d_in[0];  // (1,50,50,1024)
    const float* boxes = (const float*)d_in[1];  // (1,300,4)
    float* out = (float*)d_out;                  // (1,300,7,7,1024)

    dim3 grid(8 * 38 * PO * CHQ);   // 8512 single-wave blocks
    dim3 block(64);
    roi_pool_f32_kernel<<<grid, block, 0, stream>>>(feat, boxes, out);
}

// Round 2
// 98.769 us; speedup vs baseline: 1.0903x; 1.0903x over previous
//
#include <hip/hip_runtime.h>
#include <math.h>

// features: (1,50,50,1024) fp32 NHWC; boxes: (1,300,4) [y1,x1,y2,x2] in [0,1]
// CROP=14, POOL_K=2 -> out (1,300,7,7,1024) fp32
//
// R7: the 256 MiB workspace poison-fill is UNCONDITIONAL (R6 proved it: ws
// untouched, fills still 44-45 us/iter). So bf16-in-ws is free again ->
// restore it (halves pool-kernel cache reads; 5 MB bf16 L2-fits per XCD,
// 10 MB fp32 does not). New this round:
//  - row dedup: 2/3/4 unique bilinear rows (wave-uniform branch) -> ~22%
//    fewer load bytes+instructions
//  - 256-thread blocks (4 waves = 4 channel quarters) -> 1/4 the workgroups,
//    better per-CU packing if wg-slot-limited
#define FH 50
#define FW 50
#define FC 1024
#define FC4 256        // float4s per pixel (fp32) == uint2s per pixel (bf16)
#define NBOX 300
#define PO 7
#define CHQ 4
#define NPIX (FH * FW * FC)      // 2,560,000 elements
#define BF16_BYTES (NPIX * 2)    // 5,242,880

typedef float nat4 __attribute__((ext_vector_type(4)));

__device__ __forceinline__ nat4 lerp4(nat4 a, nat4 b, float w) {
    return a + (b - a) * w;
}
__device__ __forceinline__ nat4 max4(nat4 a, nat4 b) {
    nat4 r;
    r.x = fmaxf(a.x, b.x);
    r.y = fmaxf(a.y, b.y);
    r.z = fmaxf(a.z, b.z);
    r.w = fmaxf(a.w, b.w);
    return r;
}
// unpack 4 bf16 channels (packed little-endian in uint2) to f32
__device__ __forceinline__ nat4 bf2f(uint2 u) {
    nat4 r;
    r.x = __uint_as_float(u.x << 16);
    r.y = __uint_as_float(u.x & 0xffff0000u);
    r.z = __uint_as_float(u.y << 16);
    r.w = __uint_as_float(u.y & 0xffff0000u);
    return r;
}
__device__ __forceinline__ unsigned bfpack(float a, float b) {  // RNE to bf16
    unsigned ua = __float_as_uint(a);
    unsigned ub = __float_as_uint(b);
    ua += 0x7fffu + ((ua >> 16) & 1u);
    ub += 0x7fffu + ((ub >> 16) & 1u);
    return (ua >> 16) | (ub & 0xffff0000u);
}

// Pass 1: fp32 features -> bf16 in workspace (15 MB traffic, ~3 us).
__global__ __launch_bounds__(256) void cvt_kernel(
    const float* __restrict__ feat, unsigned* __restrict__ ws)
{
    const int i = blockIdx.x * 256 + threadIdx.x;   // float4 index, 640,000 total
    const float4 v = reinterpret_cast<const float4*>(feat)[i];
    uint2 w;
    w.x = bfpack(v.x, v.y);
    w.y = bfpack(v.z, v.w);
    reinterpret_cast<uint2*>(ws)[i] = w;
}

// Rolling NR x 2 bf16 column cache + 1-column software prefetch.
// All control flow is wave-uniform (depends only on box/py).
// Arrays are compile-time indexed after full unroll -> stay in VGPRs.
template<int NR>
__device__ __forceinline__ void pool_rows(
    const uint2* __restrict__ f2, const int (&rows)[NR], int c,
    float basex, float stepx, float wyA, float wyB,
    nat4* __restrict__ obase)
{
    uint2 cur[NR][2], nxt[NR][2];
    int cc;
    {
        const float xf = floorf(basex);
        cc = min(max((int)xf, 0), FW - 1);
        const int x1 = min(cc + 1, FW - 1);
#pragma unroll
        for (int q = 0; q < NR; ++q) {
            cur[q][0] = f2[(rows[q] + cc) * FC4 + c];
            cur[q][1] = f2[(rows[q] + x1) * FC4 + c];
        }
    }

    nat4 m = (nat4)(-INFINITY);
    for (int ix = 0; ix < 2 * PO; ++ix) {
        // ---- Prefetch: issue loads for column ix+1 (no load dependence) ----
        int d = 0;
        if (ix < 2 * PO - 1) {
            const float xsn = basex + (float)(ix + 1) * stepx;
            const int nx0 = min(max((int)floorf(xsn), 0), FW - 1);
            const int nx1 = min(nx0 + 1, FW - 1);
            d = nx0 - cc;
            if (d == 1) {
#pragma unroll
                for (int q = 0; q < NR; ++q)
                    nxt[q][1] = f2[(rows[q] + nx1) * FC4 + c];
            } else if (d >= 2) {
#pragma unroll
                for (int q = 0; q < NR; ++q) {
                    nxt[q][0] = f2[(rows[q] + nx0) * FC4 + c];
                    nxt[q][1] = f2[(rows[q] + nx1) * FC4 + c];
                }
            }
            cc = nx0;
        }

        // ---- Compute sample ix from current registers ----
        {
            const float xs = basex + (float)ix * stepx;
            const float wx = xs - floorf(xs);   // unclipped floor for the weight
            const nat4 a0 = lerp4(bf2f(cur[0][0]), bf2f(cur[0][1]), wx);
            const nat4 a1 = lerp4(bf2f(cur[1][0]), bf2f(cur[1][1]), wx);
            const nat4 vA = lerp4(a0, a1, wyA);
            nat4 vB;
            if constexpr (NR == 2) {
                vB = lerp4(a0, a1, wyB);          // B samples same row pair
            } else if constexpr (NR == 3) {
                const nat4 a2 = lerp4(bf2f(cur[2][0]), bf2f(cur[2][1]), wx);
                vB = lerp4(a1, a2, wyB);          // shares middle row with A
            } else {
                const nat4 a2 = lerp4(bf2f(cur[2][0]), bf2f(cur[2][1]), wx);
                const nat4 a3 = lerp4(bf2f(cur[3][0]), bf2f(cur[3][1]), wx);
                vB = lerp4(a2, a3, wyB);
            }
            m = max4(m, max4(vA, vB));
        }

        if (ix & 1) {
            // write-once output: NT store keeps it out of L1/L2
            __builtin_nontemporal_store(m, obase + (ix >> 1) * FC4);
            m = (nat4)(-INFINITY);
        }

        // ---- Rotate incoming -> current (wave-uniform branches) ----
        if (ix < 2 * PO - 1) {
            if (d == 1) {
#pragma unroll
                for (int q = 0; q < NR; ++q) { cur[q][0] = cur[q][1]; cur[q][1] = nxt[q][1]; }
            } else if (d >= 2) {
#pragma unroll
                for (int q = 0; q < NR; ++q) { cur[q][0] = nxt[q][0]; cur[q][1] = nxt[q][1]; }
            }
        }
    }
}

// Pass 2: one 256-thread block (4 waves = 4 channel quarters) per
// (box, pooled row). 2128 blocks. Wave-uniform row-dedup branch picks the
// 2/3/4-unique-row loop.
__global__ __launch_bounds__(256) void roi_pool_bf16_kernel(
    const unsigned* __restrict__ ws,   // bf16 features (50,50,1024)
    const float* __restrict__ boxes,   // (300,4)
    float* __restrict__ out)           // (300,7,7,1024)
{
    const int j = blockIdx.x & 7;              // XCD slot
    const int k = blockIdx.x >> 3;
    const int n = j + 8 * (k / PO);            // box->XCD affinity
    if (n >= NBOX) return;
    const int py = k % PO;                     // pooled row 0..6
    const int c  = threadIdx.x;                // uint2 index in pixel, 0..255

    const float by1 = boxes[n * 4 + 0];
    const float bx1 = boxes[n * 4 + 1];
    const float by2 = boxes[n * 4 + 2];
    const float bx2 = boxes[n * 4 + 3];

    const float stepy = (by2 - by1) * (49.0f / 13.0f);
    const float stepx = (bx2 - bx1) * (49.0f / 13.0f);
    const float basey = by1 * 49.0f;
    const float basex = bx1 * 49.0f;

    const float ysA = basey + (float)(2 * py) * stepy;
    const float ysB = ysA + stepy;
    const float fA = floorf(ysA); const float wyA = ysA - fA;
    const float fB = floorf(ysB); const float wyB = ysB - fB;
    const int y0A = min(max((int)fA, 0), FH - 1); const int y1A = min(y0A + 1, FH - 1);
    const int y0B = min(max((int)fB, 0), FH - 1); const int y1B = min(y0B + 1, FH - 1);

    const uint2* __restrict__ f2 = reinterpret_cast<const uint2*>(ws);
    nat4* __restrict__ obase =
        reinterpret_cast<nat4*>(out) + (size_t)(n * (PO * PO) + py * PO) * FC4 + c;

    if (y0B == y0A) {              // 2 unique rows (also covers y-clamped edge)
        const int rows[2] = {y0A * FW, y1A * FW};
        pool_rows<2>(f2, rows, c, basex, stepx, wyA, wyB, obase);
    } else if (y0B == y1A) {       // 3 unique rows, middle shared
        const int rows[3] = {y0A * FW, y1A * FW, y1B * FW};
        pool_rows<3>(f2, rows, c, basex, stepx, wyA, wyB, obase);
    } else {                       // 4 unique rows
        const int rows[4] = {y0A * FW, y1A * FW, y0B * FW, y1B * FW};
        pool_rows<4>(f2, rows, c, basex, stepx, wyA, wyB, obase);
    }
}

// Fallback (ws too small): fp32 single-wave rolling-cache kernel (R6).
__global__ __launch_bounds__(64) void roi_pool_f32_kernel(
    const float* __restrict__ feat,
    const float* __restrict__ boxes,
    float* __restrict__ out)
{
    const int j = blockIdx.x & 7;
    const int k = blockIdx.x >> 3;
    const int n = j + 8 * (k / (PO * CHQ));
    if (n >= NBOX) return;
    const int r  = k % (PO * CHQ);
    const int py = r >> 2;
    const int cq = r & 3;
    const int c4 = cq * 64 + threadIdx.x;

    const float by1 = boxes[n * 4 + 0];
    const float bx1 = boxes[n * 4 + 1];
    const float by2 = boxes[n * 4 + 2];
    const float bx2 = boxes[n * 4 + 3];
    const float stepy = (by2 - by1) * (49.0f / 13.0f);
    const float stepx = (bx2 - bx1) * (49.0f / 13.0f);
    const float basey = by1 * 49.0f;
    const float basex = bx1 * 49.0f;
    const float ysA = basey + (float)(2 * py) * stepy;
    const float ysB = ysA + stepy;
    const float fA = floorf(ysA); const float wyA = ysA - fA;
    const float fB = floorf(ysB); const float wyB = ysB - fB;
    const int y0A = min(max((int)fA, 0), FH - 1); const int y1A = min(y0A + 1, FH - 1);
    const int y0B = min(max((int)fB, 0), FH - 1); const int y1B = min(y0B + 1, FH - 1);

    const nat4* __restrict__ f4 = reinterpret_cast<const nat4*>(feat);
    const int rA0 = y0A * FW, rA1 = y1A * FW, rB0 = y0B * FW, rB1 = y1B * FW;

    int cc = -1000;
    nat4 A00, A01, A10, A11, B00, B01, B10, B11;
    A00 = A01 = A10 = A11 = B00 = B01 = B10 = B11 = (nat4)0.0f;
    nat4 m = (nat4)(-INFINITY);
    nat4* __restrict__ obase =
        reinterpret_cast<nat4*>(out) + (size_t)(n * (PO * PO) + py * PO) * FC4 + c4;

    for (int ix = 0; ix < 2 * PO; ++ix) {
        const float xs = basex + (float)ix * stepx;
        const float xf = floorf(xs);
        const float wx = xs - xf;
        int x0 = min(max((int)xf, 0), FW - 1);
        const int x1 = min(x0 + 1, FW - 1);
        if (x0 != cc) {
            if (x0 == cc + 1) {
                A00 = A01; A10 = A11; B00 = B01; B10 = B11;
                A01 = f4[(rA0 + x1) * FC4 + c4];
                A11 = f4[(rA1 + x1) * FC4 + c4];
                B01 = f4[(rB0 + x1) * FC4 + c4];
                B11 = f4[(rB1 + x1) * FC4 + c4];
            } else {
                A00 = f4[(rA0 + x0) * FC4 + c4];
                A01 = f4[(rA0 + x1) * FC4 + c4];
                A10 = f4[(rA1 + x0) * FC4 + c4];
                A11 = f4[(rA1 + x1) * FC4 + c4];
                B00 = f4[(rB0 + x0) * FC4 + c4];
                B01 = f4[(rB0 + x1) * FC4 + c4];
                B10 = f4[(rB1 + x0) * FC4 + c4];
                B11 = f4[(rB1 + x1) * FC4 + c4];
            }
            cc = x0;
        }
        const nat4 vA = lerp4(lerp4(A00, A01, wx), lerp4(A10, A11, wx), wyA);
        const nat4 vB = lerp4(lerp4(B00, B01, wx), lerp4(B10, B11, wx), wyB);
        m = max4(m, max4(vA, vB));
        if (ix & 1) {
            __builtin_nontemporal_store(m, obase + (ix >> 1) * FC4);
            m = (nat4)(-INFINITY);
        }
    }
}

extern "C" void kernel_launch(void* const* d_in, const int* in_sizes, int n_in,
                              void* d_out, int out_size, void* d_ws, size_t ws_size,
                              hipStream_t stream) {
    (void)in_sizes; (void)n_in; (void)out_size;
    const float* feat  = (const float*)d_in[0];  // (1,50,50,1024)
    const float* boxes = (const float*)d_in[1];  // (1,300,4)
    float* out = (float*)d_out;                  // (1,300,7,7,1024)

    if (ws_size >= (size_t)BF16_BYTES) {
        unsigned* wsb = (unsigned*)d_ws;
        cvt_kernel<<<dim3(NPIX / 4 / 256), dim3(256), 0, stream>>>(feat, wsb);
        roi_pool_bf16_kernel<<<dim3(8 * 38 * PO), dim3(256), 0, stream>>>(wsb, boxes, out);
    } else {
        roi_pool_f32_kernel<<<dim3(8 * 38 * PO * CHQ), dim3(64), 0, stream>>>(feat, boxes, out);
    }
}

// Round 3
// 96.578 us; speedup vs baseline: 1.1151x; 1.0227x over previous
//
#include <hip/hip_runtime.h>
#include <math.h>

// features: (1,50,50,1024) fp32 NHWC; boxes: (1,300,4) [y1,x1,y2,x2] in [0,1]
// CROP=14, POOL_K=2 -> out (1,300,7,7,1024) fp32
//
// R8: CHANNEL->XCD partitioning. R5-R7 established the pool kernel is
// L2-tier-bound: fp32 (10MB, L3-served) pool ~45us; bf16 (5MB, ~80% L2)
// ~31us; -22% bytes at same tier ~30us (byte-insensitive). The 5MB bf16
// map still exceeds one XCD's 4MiB L2 and every XCD reads all of it
// (box->XCD affinity gives no footprint cut: random boxes cover the map).
// This round: assign each channel-quarter (256ch = 1.28MB) to an XCD PAIR
// via blockIdx%8, so each XCD's L2 working set is 1.28MB -> fully
// resident, ~39x in-L2 reuse. Requires single-wave 64-thr blocks (a
// 256-thr block would mix all 4 quarters on one XCD) -- which also
// restores R4's TLP granularity (8400 single-wave blocks). Dedup kept.
#define FH 50
#define FW 50
#define FC 1024
#define FC4 256        // float4s per pixel (fp32) == uint2s per pixel (bf16)
#define NBOX 300
#define PO 7
#define CHQ 4
#define NPIX (FH * FW * FC)      // 2,560,000 elements
#define BF16_BYTES (NPIX * 2)    // 5,242,880

typedef float nat4 __attribute__((ext_vector_type(4)));

__device__ __forceinline__ nat4 lerp4(nat4 a, nat4 b, float w) {
    return a + (b - a) * w;
}
__device__ __forceinline__ nat4 max4(nat4 a, nat4 b) {
    nat4 r;
    r.x = fmaxf(a.x, b.x);
    r.y = fmaxf(a.y, b.y);
    r.z = fmaxf(a.z, b.z);
    r.w = fmaxf(a.w, b.w);
    return r;
}
// unpack 4 bf16 channels (packed little-endian in uint2) to f32
__device__ __forceinline__ nat4 bf2f(uint2 u) {
    nat4 r;
    r.x = __uint_as_float(u.x << 16);
    r.y = __uint_as_float(u.x & 0xffff0000u);
    r.z = __uint_as_float(u.y << 16);
    r.w = __uint_as_float(u.y & 0xffff0000u);
    return r;
}
__device__ __forceinline__ unsigned bfpack(float a, float b) {  // RNE to bf16
    unsigned ua = __float_as_uint(a);
    unsigned ub = __float_as_uint(b);
    ua += 0x7fffu + ((ua >> 16) & 1u);
    ub += 0x7fffu + ((ub >> 16) & 1u);
    return (ua >> 16) | (ub & 0xffff0000u);
}

// Pass 1: fp32 features -> bf16 in workspace (15 MB traffic, ~3 us).
__global__ __launch_bounds__(256) void cvt_kernel(
    const float* __restrict__ feat, unsigned* __restrict__ ws)
{
    const int i = blockIdx.x * 256 + threadIdx.x;   // float4 index, 640,000 total
    const float4 v = reinterpret_cast<const float4*>(feat)[i];
    uint2 w;
    w.x = bfpack(v.x, v.y);
    w.y = bfpack(v.z, v.w);
    reinterpret_cast<uint2*>(ws)[i] = w;
}

// Rolling NR x 2 bf16 column cache + 1-column software prefetch.
// All control flow is wave-uniform (depends only on box/py).
// Arrays are compile-time indexed after full unroll -> stay in VGPRs.
template<int NR>
__device__ __forceinline__ void pool_rows(
    const uint2* __restrict__ f2, const int (&rows)[NR], int c,
    float basex, float stepx, float wyA, float wyB,
    nat4* __restrict__ obase)
{
    uint2 cur[NR][2], nxt[NR][2];
    int cc;
    {
        const float xf = floorf(basex);
        cc = min(max((int)xf, 0), FW - 1);
        const int x1 = min(cc + 1, FW - 1);
#pragma unroll
        for (int q = 0; q < NR; ++q) {
            cur[q][0] = f2[(rows[q] + cc) * FC4 + c];
            cur[q][1] = f2[(rows[q] + x1) * FC4 + c];
        }
    }

    nat4 m = (nat4)(-INFINITY);
    for (int ix = 0; ix < 2 * PO; ++ix) {
        // ---- Prefetch: issue loads for column ix+1 (no load dependence) ----
        int d = 0;
        if (ix < 2 * PO - 1) {
            const float xsn = basex + (float)(ix + 1) * stepx;
            const int nx0 = min(max((int)floorf(xsn), 0), FW - 1);
            const int nx1 = min(nx0 + 1, FW - 1);
            d = nx0 - cc;
            if (d == 1) {
#pragma unroll
                for (int q = 0; q < NR; ++q)
                    nxt[q][1] = f2[(rows[q] + nx1) * FC4 + c];
            } else if (d >= 2) {
#pragma unroll
                for (int q = 0; q < NR; ++q) {
                    nxt[q][0] = f2[(rows[q] + nx0) * FC4 + c];
                    nxt[q][1] = f2[(rows[q] + nx1) * FC4 + c];
                }
            }
            cc = nx0;
        }

        // ---- Compute sample ix from current registers ----
        {
            const float xs = basex + (float)ix * stepx;
            const float wx = xs - floorf(xs);   // unclipped floor for the weight
            const nat4 a0 = lerp4(bf2f(cur[0][0]), bf2f(cur[0][1]), wx);
            const nat4 a1 = lerp4(bf2f(cur[1][0]), bf2f(cur[1][1]), wx);
            const nat4 vA = lerp4(a0, a1, wyA);
            nat4 vB;
            if constexpr (NR == 2) {
                vB = lerp4(a0, a1, wyB);          // B samples same row pair
            } else if constexpr (NR == 3) {
                const nat4 a2 = lerp4(bf2f(cur[2][0]), bf2f(cur[2][1]), wx);
                vB = lerp4(a1, a2, wyB);          // shares middle row with A
            } else {
                const nat4 a2 = lerp4(bf2f(cur[2][0]), bf2f(cur[2][1]), wx);
                const nat4 a3 = lerp4(bf2f(cur[3][0]), bf2f(cur[3][1]), wx);
                vB = lerp4(a2, a3, wyB);
            }
            m = max4(m, max4(vA, vB));
        }

        if (ix & 1) {
            // write-once output: NT store keeps it out of L1/L2
            __builtin_nontemporal_store(m, obase + (ix >> 1) * FC4);
            m = (nat4)(-INFINITY);
        }

        // ---- Rotate incoming -> current (wave-uniform branches) ----
        if (ix < 2 * PO - 1) {
            if (d == 1) {
#pragma unroll
                for (int q = 0; q < NR; ++q) { cur[q][0] = cur[q][1]; cur[q][1] = nxt[q][1]; }
            } else if (d >= 2) {
#pragma unroll
                for (int q = 0; q < NR; ++q) { cur[q][0] = nxt[q][0]; cur[q][1] = nxt[q][1]; }
            }
        }
    }
}

// Pass 2: one SINGLE-WAVE block per (box, pooled row, channel-quarter).
// blockIdx%8 (empirical XCD slot) carries the CHANNEL quarter: quarter cq
// runs only on XCDs {cq, cq+4}, so each XCD's L2 working set is one
// 256-channel slice = 1.28 MB (fully L2-resident).
__global__ __launch_bounds__(64) void roi_pool_bf16_kernel(
    const unsigned* __restrict__ ws,   // bf16 features (50,50,1024)
    const float* __restrict__ boxes,   // (300,4)
    float* __restrict__ out)           // (300,7,7,1024)
{
    const int j    = blockIdx.x & 7;           // XCD slot
    const int cq   = j & 3;                    // channel quarter -> XCD pair {cq, cq+4}
    const int g    = blockIdx.x >> 3;          // [0, 1050)
    const int unit = g * 2 + (j >> 2);         // [0, 2100) = (box, pooled row)
    const int n    = unit / 7;                 // box 0..299
    const int py   = unit - n * 7;             // pooled row 0..6
    const int c    = cq * 64 + threadIdx.x;    // uint2 index in pixel, 0..255

    const float by1 = boxes[n * 4 + 0];
    const float bx1 = boxes[n * 4 + 1];
    const float by2 = boxes[n * 4 + 2];
    const float bx2 = boxes[n * 4 + 3];

    const float stepy = (by2 - by1) * (49.0f / 13.0f);
    const float stepx = (bx2 - bx1) * (49.0f / 13.0f);
    const float basey = by1 * 49.0f;
    const float basex = bx1 * 49.0f;

    const float ysA = basey + (float)(2 * py) * stepy;
    const float ysB = ysA + stepy;
    const float fA = floorf(ysA); const float wyA = ysA - fA;
    const float fB = floorf(ysB); const float wyB = ysB - fB;
    const int y0A = min(max((int)fA, 0), FH - 1); const int y1A = min(y0A + 1, FH - 1);
    const int y0B = min(max((int)fB, 0), FH - 1); const int y1B = min(y0B + 1, FH - 1);

    const uint2* __restrict__ f2 = reinterpret_cast<const uint2*>(ws);
    nat4* __restrict__ obase =
        reinterpret_cast<nat4*>(out) + (size_t)(n * (PO * PO) + py * PO) * FC4 + c;

    if (y0B == y0A) {              // 2 unique rows (also covers y-clamped edge)
        const int rows[2] = {y0A * FW, y1A * FW};
        pool_rows<2>(f2, rows, c, basex, stepx, wyA, wyB, obase);
    } else if (y0B == y1A) {       // 3 unique rows, middle shared
        const int rows[3] = {y0A * FW, y1A * FW, y1B * FW};
        pool_rows<3>(f2, rows, c, basex, stepx, wyA, wyB, obase);
    } else {                       // 4 unique rows
        const int rows[4] = {y0A * FW, y1A * FW, y0B * FW, y1B * FW};
        pool_rows<4>(f2, rows, c, basex, stepx, wyA, wyB, obase);
    }
}

// Fallback (ws too small): fp32 single-wave rolling-cache kernel (R6).
__global__ __launch_bounds__(64) void roi_pool_f32_kernel(
    const float* __restrict__ feat,
    const float* __restrict__ boxes,
    float* __restrict__ out)
{
    const int j = blockIdx.x & 7;
    const int k = blockIdx.x >> 3;
    const int n = j + 8 * (k / (PO * CHQ));
    if (n >= NBOX) return;
    const int r  = k % (PO * CHQ);
    const int py = r >> 2;
    const int cq = r & 3;
    const int c4 = cq * 64 + threadIdx.x;

    const float by1 = boxes[n * 4 + 0];
    const float bx1 = boxes[n * 4 + 1];
    const float by2 = boxes[n * 4 + 2];
    const float bx2 = boxes[n * 4 + 3];
    const float stepy = (by2 - by1) * (49.0f / 13.0f);
    const float stepx = (bx2 - bx1) * (49.0f / 13.0f);
    const float basey = by1 * 49.0f;
    const float basex = bx1 * 49.0f;
    const float ysA = basey + (float)(2 * py) * stepy;
    const float ysB = ysA + stepy;
    const float fA = floorf(ysA); const float wyA = ysA - fA;
    const float fB = floorf(ysB); const float wyB = ysB - fB;
    const int y0A = min(max((int)fA, 0), FH - 1); const int y1A = min(y0A + 1, FH - 1);
    const int y0B = min(max((int)fB, 0), FH - 1); const int y1B = min(y0B + 1, FH - 1);

    const nat4* __restrict__ f4 = reinterpret_cast<const nat4*>(feat);
    const int rA0 = y0A * FW, rA1 = y1A * FW, rB0 = y0B * FW, rB1 = y1B * FW;

    int cc = -1000;
    nat4 A00, A01, A10, A11, B00, B01, B10, B11;
    A00 = A01 = A10 = A11 = B00 = B01 = B10 = B11 = (nat4)0.0f;
    nat4 m = (nat4)(-INFINITY);
    nat4* __restrict__ obase =
        reinterpret_cast<nat4*>(out) + (size_t)(n * (PO * PO) + py * PO) * FC4 + c4;

    for (int ix = 0; ix < 2 * PO; ++ix) {
        const float xs = basex + (float)ix * stepx;
        const float xf = floorf(xs);
        const float wx = xs - xf;
        int x0 = min(max((int)xf, 0), FW - 1);
        const int x1 = min(x0 + 1, FW - 1);
        if (x0 != cc) {
            if (x0 == cc + 1) {
                A00 = A01; A10 = A11; B00 = B01; B10 = B11;
                A01 = f4[(rA0 + x1) * FC4 + c4];
                A11 = f4[(rA1 + x1) * FC4 + c4];
                B01 = f4[(rB0 + x1) * FC4 + c4];
                B11 = f4[(rB1 + x1) * FC4 + c4];
            } else {
                A00 = f4[(rA0 + x0) * FC4 + c4];
                A01 = f4[(rA0 + x1) * FC4 + c4];
                A10 = f4[(rA1 + x0) * FC4 + c4];
                A11 = f4[(rA1 + x1) * FC4 + c4];
                B00 = f4[(rB0 + x0) * FC4 + c4];
                B01 = f4[(rB0 + x1) * FC4 + c4];
                B10 = f4[(rB1 + x0) * FC4 + c4];
                B11 = f4[(rB1 + x1) * FC4 + c4];
            }
            cc = x0;
        }
        const nat4 vA = lerp4(lerp4(A00, A01, wx), lerp4(A10, A11, wx), wyA);
        const nat4 vB = lerp4(lerp4(B00, B01, wx), lerp4(B10, B11, wx), wyB);
        m = max4(m, max4(vA, vB));
        if (ix & 1) {
            __builtin_nontemporal_store(m, obase + (ix >> 1) * FC4);
            m = (nat4)(-INFINITY);
        }
    }
}

extern "C" void kernel_launch(void* const* d_in, const int* in_sizes, int n_in,
                              void* d_out, int out_size, void* d_ws, size_t ws_size,
                              hipStream_t stream) {
    (void)in_sizes; (void)n_in; (void)out_size;
    const float* feat  = (const float*)d_in[0];  // (1,50,50,1024)
    const float* boxes = (const float*)d_in[1];  // (1,300,4)
    float* out = (float*)d_out;                  // (1,300,7,7,1024)

    if (ws_size >= (size_t)BF16_BYTES) {
        unsigned* wsb = (unsigned*)d_ws;
        cvt_kernel<<<dim3(NPIX / 4 / 256), dim3(256), 0, stream>>>(feat, wsb);
        // 8 XCD slots x 1050 = 8400 single-wave blocks; cq = slot & 3
        roi_pool_bf16_kernel<<<dim3(8 * 1050), dim3(64), 0, stream>>>(wsb, boxes, out);
    } else {
        roi_pool_f32_kernel<<<dim3(8 * 38 * PO * CHQ), dim3(64), 0, stream>>>(feat, boxes, out);
    }
}

// Round 5
// 96.480 us; speedup vs baseline: 1.1162x; 1.0010x over previous
//
#include <hip/hip_runtime.h>
#include <math.h>

// features: (1,50,50,1024) fp32 NHWC; boxes: (1,300,4) [y1,x1,y2,x2] in [0,1]
// CROP=14, POOL_K=2 -> out (1,300,7,7,1024) fp32
//
// R9b: same as R9 (uint4 16B/lane loads, channel-half->XCD partition,
// launch_bounds(64,4), NT cvt loads) with the compile fix: nontemporal
// builtins need a true clang vector type (ext_vector_type), not HIP's
// float4 class -> load via nat4.
#define FH 50
#define FW 50
#define FC 1024
#define FC4 256        // float4s per pixel (fp32 out) / nat4s per pixel
#define FC8 128        // uint4s per pixel (bf16)
#define NBOX 300
#define PO 7
#define CHQ 4
#define NPIX (FH * FW * FC)      // 2,560,000 elements
#define BF16_BYTES (NPIX * 2)    // 5,242,880

typedef float nat4 __attribute__((ext_vector_type(4)));

__device__ __forceinline__ nat4 lerp4(nat4 a, nat4 b, float w) {
    return a + (b - a) * w;
}
__device__ __forceinline__ nat4 max4(nat4 a, nat4 b) {
    nat4 r;
    r.x = fmaxf(a.x, b.x);
    r.y = fmaxf(a.y, b.y);
    r.z = fmaxf(a.z, b.z);
    r.w = fmaxf(a.w, b.w);
    return r;
}
// unpack one half (4 bf16 channels) of a uint4; HH is compile-time
template<int HH>
__device__ __forceinline__ nat4 bfh(uint4 u) {
    const unsigned a = HH ? u.z : u.x;
    const unsigned b = HH ? u.w : u.y;
    nat4 r;
    r.x = __uint_as_float(a << 16);
    r.y = __uint_as_float(a & 0xffff0000u);
    r.z = __uint_as_float(b << 16);
    r.w = __uint_as_float(b & 0xffff0000u);
    return r;
}
__device__ __forceinline__ unsigned bfpack(float a, float b) {  // RNE to bf16
    unsigned ua = __float_as_uint(a);
    unsigned ub = __float_as_uint(b);
    ua += 0x7fffu + ((ua >> 16) & 1u);
    ub += 0x7fffu + ((ub >> 16) & 1u);
    return (ua >> 16) | (ub & 0xffff0000u);
}

// Pass 1: fp32 features -> bf16 in workspace (15 MB traffic, ~3 us).
// NT loads: feat is touch-once here; don't evict the ws from L2.
__global__ __launch_bounds__(256) void cvt_kernel(
    const float* __restrict__ feat, unsigned* __restrict__ ws)
{
    const int i = blockIdx.x * 256 + threadIdx.x;   // nat4 index, 640,000 total
    const nat4 v = __builtin_nontemporal_load(
        reinterpret_cast<const nat4*>(feat) + i);
    uint2 w;
    w.x = bfpack(v.x, v.y);
    w.y = bfpack(v.z, v.w);
    reinterpret_cast<uint2*>(ws)[i] = w;
}

// Rolling NR x 2 bf16 column cache (uint4 = 8 channels/lane) + 1-column
// software prefetch. All control flow wave-uniform; arrays compile-time
// indexed after full unroll -> stay in VGPRs.
template<int NR>
__device__ __forceinline__ void pool_rows(
    const uint4* __restrict__ f4, const int (&rows)[NR], int c,
    float basex, float stepx, float wyA, float wyB,
    nat4* __restrict__ obase)
{
    uint4 cur[NR][2], nxt[NR][2];
    int cc;
    {
        const float xf = floorf(basex);
        cc = min(max((int)xf, 0), FW - 1);
        const int x1 = min(cc + 1, FW - 1);
#pragma unroll
        for (int q = 0; q < NR; ++q) {
            cur[q][0] = f4[(rows[q] + cc) * FC8 + c];
            cur[q][1] = f4[(rows[q] + x1) * FC8 + c];
        }
    }

    nat4 m0 = (nat4)(-INFINITY), m1 = (nat4)(-INFINITY);
    for (int ix = 0; ix < 2 * PO; ++ix) {
        // ---- Prefetch: issue loads for column ix+1 (no load dependence) ----
        int d = 0;
        if (ix < 2 * PO - 1) {
            const float xsn = basex + (float)(ix + 1) * stepx;
            const int nx0 = min(max((int)floorf(xsn), 0), FW - 1);
            const int nx1 = min(nx0 + 1, FW - 1);
            d = nx0 - cc;
            if (d == 1) {
#pragma unroll
                for (int q = 0; q < NR; ++q)
                    nxt[q][1] = f4[(rows[q] + nx1) * FC8 + c];
            } else if (d >= 2) {
#pragma unroll
                for (int q = 0; q < NR; ++q) {
                    nxt[q][0] = f4[(rows[q] + nx0) * FC8 + c];
                    nxt[q][1] = f4[(rows[q] + nx1) * FC8 + c];
                }
            }
            cc = nx0;
        }

        // ---- Compute sample ix from current registers (both 4-ch halves) ----
        {
            const float xs = basex + (float)ix * stepx;
            const float wx = xs - floorf(xs);   // unclipped floor for the weight
            {   // half 0
                nat4 a[NR];
#pragma unroll
                for (int q = 0; q < NR; ++q)
                    a[q] = lerp4(bfh<0>(cur[q][0]), bfh<0>(cur[q][1]), wx);
                const nat4 vA = lerp4(a[0], a[1], wyA);
                nat4 vB;
                if constexpr (NR == 2)      vB = lerp4(a[0], a[1], wyB);
                else if constexpr (NR == 3) vB = lerp4(a[1], a[2], wyB);
                else                        vB = lerp4(a[2], a[3], wyB);
                m0 = max4(m0, max4(vA, vB));
            }
            {   // half 1
                nat4 a[NR];
#pragma unroll
                for (int q = 0; q < NR; ++q)
                    a[q] = lerp4(bfh<1>(cur[q][0]), bfh<1>(cur[q][1]), wx);
                const nat4 vA = lerp4(a[0], a[1], wyA);
                nat4 vB;
                if constexpr (NR == 2)      vB = lerp4(a[0], a[1], wyB);
                else if constexpr (NR == 3) vB = lerp4(a[1], a[2], wyB);
                else                        vB = lerp4(a[2], a[3], wyB);
                m1 = max4(m1, max4(vA, vB));
            }
        }

        if (ix & 1) {
            // write-once output: NT stores keep it out of L1/L2
            __builtin_nontemporal_store(m0, obase + (ix >> 1) * FC4);
            __builtin_nontemporal_store(m1, obase + (ix >> 1) * FC4 + 1);
            m0 = (nat4)(-INFINITY);
            m1 = (nat4)(-INFINITY);
        }

        // ---- Rotate incoming -> current (wave-uniform branches) ----
        if (ix < 2 * PO - 1) {
            if (d == 1) {
#pragma unroll
                for (int q = 0; q < NR; ++q) { cur[q][0] = cur[q][1]; cur[q][1] = nxt[q][1]; }
            } else if (d >= 2) {
#pragma unroll
                for (int q = 0; q < NR; ++q) { cur[q][0] = nxt[q][0]; cur[q][1] = nxt[q][1]; }
            }
        }
    }
}

// Pass 2: one SINGLE-WAVE block per (box, pooled row, channel-HALF).
// blockIdx%8 (empirical XCD slot): bit0 carries the channel half, so half h
// runs only on XCDs {h, h+2, h+4, h+6}; each XCD's L2 working set is one
// 512-channel slice = 2.56 MB (L2-resident). 4200 blocks.
__global__ __launch_bounds__(64, 4) void roi_pool_bf16_kernel(
    const unsigned* __restrict__ ws,   // bf16 features (50,50,1024)
    const float* __restrict__ boxes,   // (300,4)
    float* __restrict__ out)           // (300,7,7,1024)
{
    const int j    = blockIdx.x & 7;           // XCD slot
    const int h    = j & 1;                    // channel half -> 4 XCDs
    const int g    = blockIdx.x >> 3;          // [0, 525)
    const int unit = g * 4 + (j >> 1);         // [0, 2100) = (box, pooled row)
    const int n    = unit / 7;                 // box 0..299
    const int py   = unit - n * 7;             // pooled row 0..6
    const int c    = h * 64 + threadIdx.x;     // uint4 index in pixel, 0..127

    const float by1 = boxes[n * 4 + 0];
    const float bx1 = boxes[n * 4 + 1];
    const float by2 = boxes[n * 4 + 2];
    const float bx2 = boxes[n * 4 + 3];

    const float stepy = (by2 - by1) * (49.0f / 13.0f);
    const float stepx = (bx2 - bx1) * (49.0f / 13.0f);
    const float basey = by1 * 49.0f;
    const float basex = bx1 * 49.0f;

    const float ysA = basey + (float)(2 * py) * stepy;
    const float ysB = ysA + stepy;
    const float fA = floorf(ysA); const float wyA = ysA - fA;
    const float fB = floorf(ysB); const float wyB = ysB - fB;
    const int y0A = min(max((int)fA, 0), FH - 1); const int y1A = min(y0A + 1, FH - 1);
    const int y0B = min(max((int)fB, 0), FH - 1); const int y1B = min(y0B + 1, FH - 1);

    const uint4* __restrict__ f4 = reinterpret_cast<const uint4*>(ws);
    // lane covers channels [8c, 8c+8) = nat4 indices 2c, 2c+1 of the pixel
    nat4* __restrict__ obase =
        reinterpret_cast<nat4*>(out) + (size_t)(n * (PO * PO) + py * PO) * FC4 + 2 * c;

    if (y0B == y0A) {              // 2 unique rows (also covers y-clamped edge)
        const int rows[2] = {y0A * FW, y1A * FW};
        pool_rows<2>(f4, rows, c, basex, stepx, wyA, wyB, obase);
    } else if (y0B == y1A) {       // 3 unique rows, middle shared
        const int rows[3] = {y0A * FW, y1A * FW, y1B * FW};
        pool_rows<3>(f4, rows, c, basex, stepx, wyA, wyB, obase);
    } else {                       // 4 unique rows
        const int rows[4] = {y0A * FW, y1A * FW, y0B * FW, y1B * FW};
        pool_rows<4>(f4, rows, c, basex, stepx, wyA, wyB, obase);
    }
}

// Fallback (ws too small): fp32 single-wave rolling-cache kernel (R6).
__global__ __launch_bounds__(64) void roi_pool_f32_kernel(
    const float* __restrict__ feat,
    const float* __restrict__ boxes,
    float* __restrict__ out)
{
    const int j = blockIdx.x & 7;
    const int k = blockIdx.x >> 3;
    const int n = j + 8 * (k / (PO * CHQ));
    if (n >= NBOX) return;
    const int r  = k % (PO * CHQ);
    const int py = r >> 2;
    const int cq = r & 3;
    const int c4 = cq * 64 + threadIdx.x;

    const float by1 = boxes[n * 4 + 0];
    const float bx1 = boxes[n * 4 + 1];
    const float by2 = boxes[n * 4 + 2];
    const float bx2 = boxes[n * 4 + 3];
    const float stepy = (by2 - by1) * (49.0f / 13.0f);
    const float stepx = (bx2 - bx1) * (49.0f / 13.0f);
    const float basey = by1 * 49.0f;
    const float basex = bx1 * 49.0f;
    const float ysA = basey + (float)(2 * py) * stepy;
    const float ysB = ysA + stepy;
    const float fA = floorf(ysA); const float wyA = ysA - fA;
    const float fB = floorf(ysB); const float wyB = ysB - fB;
    const int y0A = min(max((int)fA, 0), FH - 1); const int y1A = min(y0A + 1, FH - 1);
    const int y0B = min(max((int)fB, 0), FH - 1); const int y1B = min(y0B + 1, FH - 1);

    const nat4* __restrict__ f4 = reinterpret_cast<const nat4*>(feat);
    const int rA0 = y0A * FW, rA1 = y1A * FW, rB0 = y0B * FW, rB1 = y1B * FW;

    int cc = -1000;
    nat4 A00, A01, A10, A11, B00, B01, B10, B11;
    A00 = A01 = A10 = A11 = B00 = B01 = B10 = B11 = (nat4)0.0f;
    nat4 m = (nat4)(-INFINITY);
    nat4* __restrict__ obase =
        reinterpret_cast<nat4*>(out) + (size_t)(n * (PO * PO) + py * PO) * FC4 + c4;

    for (int ix = 0; ix < 2 * PO; ++ix) {
        const float xs = basex + (float)ix * stepx;
        const float xf = floorf(xs);
        const float wx = xs - xf;
        int x0 = min(max((int)xf, 0), FW - 1);
        const int x1 = min(x0 + 1, FW - 1);
        if (x0 != cc) {
            if (x0 == cc + 1) {
                A00 = A01; A10 = A11; B00 = B01; B10 = B11;
                A01 = f4[(rA0 + x1) * FC4 + c4];
                A11 = f4[(rA1 + x1) * FC4 + c4];
                B01 = f4[(rB0 + x1) * FC4 + c4];
                B11 = f4[(rB1 + x1) * FC4 + c4];
            } else {
                A00 = f4[(rA0 + x0) * FC4 + c4];
                A01 = f4[(rA0 + x1) * FC4 + c4];
                A10 = f4[(rA1 + x0) * FC4 + c4];
                A11 = f4[(rA1 + x1) * FC4 + c4];
                B00 = f4[(rB0 + x0) * FC4 + c4];
                B01 = f4[(rB0 + x1) * FC4 + c4];
                B10 = f4[(rB1 + x0) * FC4 + c4];
                B11 = f4[(rB1 + x1) * FC4 + c4];
            }
            cc = x0;
        }
        const nat4 vA = lerp4(lerp4(A00, A01, wx), lerp4(A10, A11, wx), wyA);
        const nat4 vB = lerp4(lerp4(B00, B01, wx), lerp4(B10, B11, wx), wyB);
        m = max4(m, max4(vA, vB));
        if (ix & 1) {
            __builtin_nontemporal_store(m, obase + (ix >> 1) * FC4);
            m = (nat4)(-INFINITY);
        }
    }
}

extern "C" void kernel_launch(void* const* d_in, const int* in_sizes, int n_in,
                              void* d_out, int out_size, void* d_ws, size_t ws_size,
                              hipStream_t stream) {
    (void)in_sizes; (void)n_in; (void)out_size;
    const float* feat  = (const float*)d_in[0];  // (1,50,50,1024)
    const float* boxes = (const float*)d_in[1];  // (1,300,4)
    float* out = (float*)d_out;                  // (1,300,7,7,1024)

    if (ws_size >= (size_t)BF16_BYTES) {
        unsigned* wsb = (unsigned*)d_ws;
        cvt_kernel<<<dim3(NPIX / 4 / 256), dim3(256), 0, stream>>>(feat, wsb);
        // 8 XCD slots x 525 = 4200 single-wave blocks; half = slot & 1
        roi_pool_bf16_kernel<<<dim3(8 * 525), dim3(64), 0, stream>>>(wsb, boxes, out);
    } else {
        roi_pool_f32_kernel<<<dim3(8 * 38 * PO * CHQ), dim3(64), 0, stream>>>(feat, boxes, out);
    }
}